// Round 5
// baseline (132.788 us; speedup 1.0000x reference)
//
#include <hip/hip_runtime.h>
#include <hip/hip_bf16.h>
#include <cstdint>

// adknnLoss: N=8192, M=128.
//   A = L*X; B = (X@Wnet + bnet)*X
//   dist[i,j] = ||A_i - B_j||; drum = exp(-dist)
//   pred = (drum@Y)/drum.sum(1); loss = sum((Y-pred)^2)
//
// Round 5:
//  - Row-major bf16 Abf/Bbf (no swizzle: a 16x64B row-gather hits the same
//    L2 sectors as a 1KB coalesced load).
//  - pairwise: 64 rows/wave (rt=4) -> 4x less B traffic than r4; 2-deep
//    register pipeline; no LDS/barriers; grid (32,16) = 2 blocks/CU.
//  - prep: bf16 MFMA, TRANSPOSED net-GEMM (Wnet^T as A-operand) so D lands
//    with row = lane&15 -> direct row-major dword stores, no transpose.
//  - w = exp(-dist) = 2^(-sqrt(K2*d2)), K2=(log2 e)^2 folded into norms;
//    norms from bf16-rounded a/b so d2 >= ~0.

#define N_ 8192
#define K2_ 2.0813689810056077f      // (log2 e)^2
#define NEG2K2_ -4.1627379620112154f // -2*(log2 e)^2

typedef __bf16 bf16x8 __attribute__((ext_vector_type(8)));
typedef float  f32x4  __attribute__((ext_vector_type(4)));

// pack two fp32 -> bf16 RNE pair (low = f0, high = f1)
__device__ __forceinline__ uint32_t pk2(float f0, float f1) {
    uint32_t u0 = __float_as_uint(f0), u1 = __float_as_uint(f1);
    u0 = u0 + 0x7fffu + ((u0 >> 16) & 1u);
    u1 = u1 + 0x7fffu + ((u1 >> 16) & 1u);
    return (u0 >> 16) | (u1 & 0xffff0000u);
}
// same, also returning the rounded values (for norms)
__device__ __forceinline__ uint32_t rne2(float f0, float f1, float& r0, float& r1) {
    uint32_t u0 = __float_as_uint(f0), u1 = __float_as_uint(f1);
    uint32_t t0 = u0 + 0x7fffu + ((u0 >> 16) & 1u);
    uint32_t t1 = u1 + 0x7fffu + ((u1 >> 16) & 1u);
    r0 = __uint_as_float(t0 & 0xffff0000u);
    r1 = __uint_as_float(t1 & 0xffff0000u);
    return (t0 >> 16) | (t1 & 0xffff0000u);
}

// ---------------------------------------------------------------------------
// prep: 512 blocks x 64 thr (1 wave, 16 rows). No LDS, no barriers.
// net-GEMM transposed: D[m=col][n=row] = sum_c Wnet[c][col] * X[row][c]
//   A-operand (wfrag): m=ln16 -> col=ct*16+ln16, k=c=ks*32+quad*8+j (gather)
//   B-operand (xfrag): n=ln16 -> row=row0+ln16,  k=c (contiguous 16B loads)
//   D: lane -> (col = ct*16+quad*4+reg, row = row0+ln16)
// Epilogue: b=(D+bnet)*X, a=L*X, RNE->bf16 pairs, row-major dword stores,
// norms reduced over quads via shfl_xor(16|32). Zeros sumw/sumwy.
// ---------------------------------------------------------------------------
__global__ __launch_bounds__(64) void prep_kernel(
    const float* __restrict__ L, const float* __restrict__ X,
    const float* __restrict__ Y, const float* __restrict__ Wnet,
    const float* __restrict__ bnet,
    unsigned short* __restrict__ Abf, unsigned short* __restrict__ Bbf,
    float* __restrict__ naS, float2* __restrict__ nbY,
    float* __restrict__ sumw, float* __restrict__ sumwy)
{
    const int lane = threadIdx.x;
    const int ln16 = lane & 15;
    const int quad = lane >> 4;
    const int row0 = blockIdx.x * 16;
    const int row  = row0 + ln16;

    // X rows as B-operand fragments (and keep the tile L1-hot for epilogue)
    bf16x8 xfrag[4];
    #pragma unroll
    for (int ks = 0; ks < 4; ++ks) {
        const float* xp = X + (size_t)row * 128 + ks * 32 + quad * 8;
        const float4 f0 = *(const float4*)xp;
        const float4 f1 = *(const float4*)(xp + 4);
        uint4 u = make_uint4(pk2(f0.x, f0.y), pk2(f0.z, f0.w),
                             pk2(f1.x, f1.y), pk2(f1.z, f1.w));
        xfrag[ks] = *(bf16x8*)&u;
    }
    // L tile upfront in D-layout (one HBM round-trip)
    float2 Lpre[8][2];
    #pragma unroll
    for (int ct = 0; ct < 8; ++ct) {
        const float* lp = L + (size_t)row * 128 + ct * 16 + quad * 4;
        Lpre[ct][0] = *(const float2*)lp;
        Lpre[ct][1] = *(const float2*)(lp + 2);
    }

    float na_ = 0.f, nb_ = 0.f;
    #pragma unroll
    for (int ct = 0; ct < 8; ++ct) {
        // Wnet^T fragment gather: 64B-coalesced per (ks,j) across lanes
        bf16x8 wfrag[4];
        #pragma unroll
        for (int ks = 0; ks < 4; ++ks) {
            float wv[8];
            #pragma unroll
            for (int j = 0; j < 8; ++j)
                wv[j] = Wnet[(ks * 32 + quad * 8 + j) * 128 + ct * 16 + ln16];
            uint4 u = make_uint4(pk2(wv[0], wv[1]), pk2(wv[2], wv[3]),
                                 pk2(wv[4], wv[5]), pk2(wv[6], wv[7]));
            wfrag[ks] = *(bf16x8*)&u;
        }
        f32x4 s = {0.f, 0.f, 0.f, 0.f};
        #pragma unroll
        for (int ks = 0; ks < 4; ++ks)
            s = __builtin_amdgcn_mfma_f32_16x16x32_bf16(wfrag[ks], xfrag[ks], s, 0, 0, 0);

        #pragma unroll
        for (int pr = 0; pr < 2; ++pr) {
            const int colb = ct * 16 + quad * 4 + pr * 2;
            const float2 x2  = *(const float2*)(X + (size_t)row * 128 + colb);
            const float2 bn2 = *(const float2*)(bnet + colb);
            const float2 l2  = Lpre[ct][pr];
            float b0 = (s[pr * 2 + 0] + bn2.x) * x2.x;
            float b1 = (s[pr * 2 + 1] + bn2.y) * x2.y;
            float a0 = l2.x * x2.x;
            float a1 = l2.y * x2.y;
            float ra0, ra1, rb0, rb1;
            uint32_t pa = rne2(a0, a1, ra0, ra1);
            uint32_t pb = rne2(b0, b1, rb0, rb1);
            na_ = fmaf(ra0, ra0, na_); na_ = fmaf(ra1, ra1, na_);
            nb_ = fmaf(rb0, rb0, nb_); nb_ = fmaf(rb1, rb1, nb_);
            const size_t off = (size_t)row * 128 + colb;
            *(uint32_t*)(Abf + off) = pa;
            *(uint32_t*)(Bbf + off) = pb;
        }
    }

    // reduce norms over the 4 quads (same row = ln16)
    na_ += __shfl_xor(na_, 16, 64);  na_ += __shfl_xor(na_, 32, 64);
    nb_ += __shfl_xor(nb_, 16, 64);  nb_ += __shfl_xor(nb_, 32, 64);
    if (quad == 0)      naS[row] = K2_ * na_;
    else if (quad == 1) nbY[row] = make_float2(K2_ * nb_, Y[row]);
    else if (quad == 2) sumw[row] = 0.f;
    else                sumwy[row] = 0.f;
}

// ---------------------------------------------------------------------------
// pairwise: grid (32, 16), 256 thr (4 waves), 64 rows/wave (rt=4), 512-col
// chunk = 32 groups of 16. No LDS, no barriers; 2-deep register pipeline on
// B fragments. Prefetch over-reads <=2 groups past chunk end (stays in d_ws).
// ---------------------------------------------------------------------------
__global__ __launch_bounds__(256, 2) void pairwise_kernel(
    const unsigned short* __restrict__ Abf, const unsigned short* __restrict__ Bbf,
    const float* __restrict__ naS, const float2* __restrict__ nbY,
    float* __restrict__ sumw, float* __restrict__ sumwy)
{
    const int tid  = threadIdx.x;
    const int wv   = tid >> 6;
    const int lane = tid & 63;
    const int ln16 = lane & 15;
    const int quad = lane >> 4;
    const int i0   = blockIdx.x * 256 + wv * 64;
    const int j0   = blockIdx.y * 512;

    bf16x8 afrag[4][4];
    float  na[4][4];
    #pragma unroll
    for (int rt = 0; rt < 4; ++rt) {
        const unsigned short* ap = Abf + (size_t)(i0 + rt * 16 + ln16) * 128 + quad * 8;
        #pragma unroll
        for (int ks = 0; ks < 4; ++ks)
            afrag[rt][ks] = *(const bf16x8*)(ap + ks * 32);
        const f32x4 nv4 = *(const f32x4*)(naS + i0 + rt * 16 + quad * 4);
        #pragma unroll
        for (int r = 0; r < 4; ++r) na[rt][r] = nv4[r];
    }

    float accw[4][4], accwy[4][4];
    #pragma unroll
    for (int rt = 0; rt < 4; ++rt)
        #pragma unroll
        for (int r = 0; r < 4; ++r) { accw[rt][r] = 0.f; accwy[rt][r] = 0.f; }

    const unsigned short* bb = Bbf + (size_t)(j0 + ln16) * 128 + quad * 8;
    const float2* nbb = nbY + j0 + ln16;

    bf16x8 b0[4], b1[4];
    float2 nv0, nv1;
    #pragma unroll
    for (int ks = 0; ks < 4; ++ks) {
        b0[ks] = *(const bf16x8*)(bb + ks * 32);
        b1[ks] = *(const bf16x8*)(bb + 2048 + ks * 32);
    }
    nv0 = nbb[0];
    nv1 = nbb[16];

    for (int ct = 0; ct < 32; ct += 2) {
        // ---- stage 0: compute ct (b0), prefetch ct+2 ----
        {
            f32x4 s[4];
            #pragma unroll
            for (int rt = 0; rt < 4; ++rt) {
                s[rt] = (f32x4){0.f, 0.f, 0.f, 0.f};
                #pragma unroll
                for (int ks = 0; ks < 4; ++ks)
                    s[rt] = __builtin_amdgcn_mfma_f32_16x16x32_bf16(afrag[rt][ks], b0[ks], s[rt], 0, 0, 0);
            }
            const unsigned short* bp = bb + (size_t)(ct + 2) * 2048;
            const float nb = nv0.x, yj = nv0.y;
            #pragma unroll
            for (int ks = 0; ks < 4; ++ks)
                b0[ks] = *(const bf16x8*)(bp + ks * 32);
            nv0 = nbb[(ct + 2) * 16];
            #pragma unroll
            for (int rt = 0; rt < 4; ++rt)
                #pragma unroll
                for (int r = 0; r < 4; ++r) {
                    float d2 = fmaf(NEG2K2_, s[rt][r], na[rt][r] + nb);
                    d2 = fmaxf(d2, 0.f);
                    float w = __builtin_amdgcn_exp2f(-__builtin_amdgcn_sqrtf(d2));
                    accw[rt][r] += w;
                    accwy[rt][r] = fmaf(w, yj, accwy[rt][r]);
                }
        }
        // ---- stage 1: compute ct+1 (b1), prefetch ct+3 ----
        {
            f32x4 s[4];
            #pragma unroll
            for (int rt = 0; rt < 4; ++rt) {
                s[rt] = (f32x4){0.f, 0.f, 0.f, 0.f};
                #pragma unroll
                for (int ks = 0; ks < 4; ++ks)
                    s[rt] = __builtin_amdgcn_mfma_f32_16x16x32_bf16(afrag[rt][ks], b1[ks], s[rt], 0, 0, 0);
            }
            const unsigned short* bp = bb + (size_t)(ct + 3) * 2048;
            const float nb = nv1.x, yj = nv1.y;
            #pragma unroll
            for (int ks = 0; ks < 4; ++ks)
                b1[ks] = *(const bf16x8*)(bp + ks * 32);
            nv1 = nbb[(ct + 3) * 16];
            #pragma unroll
            for (int rt = 0; rt < 4; ++rt)
                #pragma unroll
                for (int r = 0; r < 4; ++r) {
                    float d2 = fmaf(NEG2K2_, s[rt][r], na[rt][r] + nb);
                    d2 = fmaxf(d2, 0.f);
                    float w = __builtin_amdgcn_exp2f(-__builtin_amdgcn_sqrtf(d2));
                    accw[rt][r] += w;
                    accwy[rt][r] = fmaf(w, yj, accwy[rt][r]);
                }
        }
    }

    // reduce over the 16 column-lanes, one atomic per row
    #pragma unroll
    for (int rt = 0; rt < 4; ++rt)
        #pragma unroll
        for (int r = 0; r < 4; ++r) {
            float w  = accw[rt][r];
            float wy = accwy[rt][r];
            #pragma unroll
            for (int m = 1; m <= 8; m <<= 1) {
                w  += __shfl_xor(w,  m, 64);
                wy += __shfl_xor(wy, m, 64);
            }
            if (ln16 == 0) {
                int rowi = i0 + rt * 16 + quad * 4 + r;
                atomicAdd(&sumw[rowi],  w);
                atomicAdd(&sumwy[rowi], wy);
            }
        }
}

// ---------------------------------------------------------------------------
__global__ __launch_bounds__(1024) void finish_kernel(
    const float* __restrict__ Y, const float* __restrict__ sumw,
    const float* __restrict__ sumwy, float* __restrict__ out)
{
    __shared__ float red[16];
    const int tid = threadIdx.x;
    float acc = 0.f;
    #pragma unroll
    for (int i = 0; i < 2; ++i) {
        int idx = tid + i * 1024;
        float4 w4  = ((const float4*)sumw)[idx];
        float4 wy4 = ((const float4*)sumwy)[idx];
        float4 y4  = ((const float4*)Y)[idx];
        const float we[4]  = {w4.x, w4.y, w4.z, w4.w};
        const float wye[4] = {wy4.x, wy4.y, wy4.z, wy4.w};
        const float ye[4]  = {y4.x, y4.y, y4.z, y4.w};
        #pragma unroll
        for (int e = 0; e < 4; ++e) {
            float pred = wye[e] * __builtin_amdgcn_rcpf(we[e]);
            float d = ye[e] - pred;
            acc = fmaf(d, d, acc);
        }
    }
    #pragma unroll
    for (int m = 1; m < 64; m <<= 1) acc += __shfl_xor(acc, m, 64);
    if ((tid & 63) == 0) red[tid >> 6] = acc;
    __syncthreads();
    if (tid < 64) {
        float v = (tid < 16) ? red[tid] : 0.f;
        #pragma unroll
        for (int m = 1; m < 16; m <<= 1) v += __shfl_xor(v, m, 64);
        if (tid == 0) out[0] = v;
    }
}

// ---------------------------------------------------------------------------
extern "C" void kernel_launch(void* const* d_in, const int* in_sizes, int n_in,
                              void* d_out, int out_size, void* d_ws, size_t ws_size,
                              hipStream_t stream)
{
    const float* L    = (const float*)d_in[0];
    const float* X    = (const float*)d_in[1];
    const float* Y    = (const float*)d_in[2];
    const float* Wnet = (const float*)d_in[3];
    const float* bnet = (const float*)d_in[4];
    float* out = (float*)d_out;

    // ws: Abf 2MB | Bbf 2MB | naS 32KB | nbY 64KB | sumw 32KB | sumwy 32KB
    char* ws = (char*)d_ws;
    unsigned short* Abf = (unsigned short*)(ws);
    unsigned short* Bbf = (unsigned short*)(ws + (size_t)2 * 1024 * 1024);
    float*  naS   = (float*) (ws + (size_t)4 * 1024 * 1024);
    float2* nbYp  = (float2*)(ws + (size_t)4 * 1024 * 1024 + 32 * 1024);
    float*  sumw  = (float*) (ws + (size_t)4 * 1024 * 1024 + 96 * 1024);
    float*  sumwy = (float*) (ws + (size_t)4 * 1024 * 1024 + 128 * 1024);

    prep_kernel<<<N_ / 16, 64, 0, stream>>>(L, X, Y, Wnet, bnet,
                                            Abf, Bbf, naS, nbYp, sumw, sumwy);
    pairwise_kernel<<<dim3(N_ / 256, 16), 256, 0, stream>>>(Abf, Bbf, naS, nbYp,
                                                            sumw, sumwy);
    finish_kernel<<<1, 1024, 0, stream>>>(Y, sumw, sumwy, out);
}